// Round 3
// baseline (238.053 us; speedup 1.0000x reference)
//
#include <hip/hip_runtime.h>
#include <math.h>

#define B_ 2
#define C_ 32
#define H_ 256
#define W_ 256
#define HW_ (H_ * W_)
#define EPS 1e-20f
#define REC 48        // floats per per-channel weight record (16B-aligned)
#define NW2 1570      // 32*REC + 32 bias + 2 inv-sums

// Record layout (per input channel c, at P[c*REC]):
//   [0..8]   sw[c][j] (softplus spatial weights, j=r*3+cc)
//   [9]      pad
//   [10]     w_g[c] (softplus)
//   [11]     1/(1+w_g[c])
//   [12..43] cwT[c][o] = softplus(channel_weight[o][c])  (o-contiguous)
//   [44..47] pad
// Tail: P[1536..1567] bias[o]; P[1568] 1/sum(sw); P[1569] 1/sum(cw)

__device__ __forceinline__ float softplus_f(float x) {
  // jax.nn.softplus == max(x,0) + log1p(exp(-|x|))
  return fmaxf(x, 0.f) + log1pf(expf(-fabsf(x)));
}

__global__ void prep_kernel(const float* __restrict__ w_grad,
                            const float* __restrict__ sweight,
                            const float* __restrict__ cweight,
                            const float* __restrict__ bias,
                            float* __restrict__ P) {
  const int t = threadIdx.x;  // 1024 threads, 1 block
  float swv = 0.f, cwv = 0.f;
  if (t < 288) {
    float s = softplus_f(sweight[t]);
    P[(t / 9) * REC + (t % 9)] = s;
    swv = s;
  }
  {
    float s = softplus_f(cweight[t]);  // t = o*32 + i
    P[(t & 31) * REC + 12 + (t >> 5)] = s;
    cwv = s;
  }
  if (t < 32) {
    float wg = softplus_f(w_grad[t]);
    P[t * REC + 10] = wg;
    P[t * REC + 11] = 1.f / (1.f + wg);
    P[1536 + t] = bias[t];
  }
#pragma unroll
  for (int off = 32; off > 0; off >>= 1) {
    swv += __shfl_down(swv, off);
    cwv += __shfl_down(cwv, off);
  }
  __shared__ float s_sw[16], s_cw[16];
  const int wave = t >> 6, lane = t & 63;
  if (lane == 0) { s_sw[wave] = swv; s_cw[wave] = cwv; }
  __syncthreads();
  if (t == 0) {
    float a = 0.f, b = 0.f;
#pragma unroll
    for (int i = 0; i < 16; ++i) { a += s_sw[i]; b += s_cw[i]; }
    P[1568] = 1.f / a;
    P[1569] = 1.f / b;
  }
}

// Block = 32x8 pixel tile (256 threads). Grid = 8 wtiles * 32 htiles * 2 b = 512.
__global__ __launch_bounds__(256) void fused_kernel(
    const float* __restrict__ d, const float* __restrict__ cd,
    const float* __restrict__ gx, const float* __restrict__ cgx,
    const float* __restrict__ gy, const float* __restrict__ cgy,
    const float* __restrict__ P, float* __restrict__ out) {
  __shared__ __align__(16) float sP[NW2];
  for (int i = threadIdx.x; i < NW2; i += 256) sP[i] = P[i];
  __syncthreads();

  // XCD-chunked bijective swizzle: 512 blocks, 8 XCDs, 64 consecutive works
  // per XCD slab; consecutive works are vertically-adjacent tiles -> L2 reuse.
  const int wid = (blockIdx.x & 7) * 64 + (blockIdx.x >> 3);
  const int b = wid >> 8;
  const int rem = wid & 255;
  const int w = (rem >> 5) * 32 + (threadIdx.x & 31);
  const int h = (rem & 31) * 8 + (threadIdx.x >> 5);

  const int base0 = b * C_ * HW_ + h * W_ + w;
  const float inv_sum_sw = sP[1568];
  const float inv_sum_cw = sP[1569];

  const bool okl = (w > 0), okr = (w < W_ - 1);
  const bool oku = (h > 0), okd = (h < H_ - 1);

  // channel-mix accumulators (statically indexed; o-loops are unrolled)
  float no[C_], de[C_];
#pragma unroll
  for (int o = 0; o < C_; ++o) { no[o] = 0.f; de[o] = 0.f; }

#pragma unroll 1  // keep rolled: small I$, low VGPR; ILP comes from 46 loads
  for (int c = 0; c < C_; ++c) {
    const int base = base0 + c * HW_;
    const float4* rec4 = (const float4*)(sP + c * REC);
    const float4 sw03 = rec4[0];
    const float4 sw47 = rec4[1];
    const float sw_arr[9] = {sw03.x, sw03.y, sw03.z, sw03.w,
                             sw47.x, sw47.y, sw47.z, sw47.w,
                             sP[c * REC + 8]};
    const float wg = sP[c * REC + 10], inv1 = sP[c * REC + 11];

    const float d_c = d[base], cd_c = cd[base];
    const float gx_c = gx[base], cgx_c = cgx[base];
    const float gy_c = gy[base], cgy_c = cgy[base];
    const float cgxgx = cgx_c * gx_c;
    const float cgygy = cgy_c * gy_c;
    const float cgx_eps = cgx_c + EPS;
    const float cgy_eps = cgy_c + EPS;

    // center tap (j=4): g_prop = 0, cg_prop = 0 exactly
    float nom, den;
    {
      const float cdp = cd_c * inv1;
      nom = cdp * d_c * sw_arr[4];
      den = cdp * sw_arr[4];
    }
#pragma unroll
    for (int r = 0; r < 3; ++r) {
#pragma unroll
      for (int cc = 0; cc < 3; ++cc) {
        const int dr = r - 1, dc = cc - 1;
        if (dr == 0 && dc == 0) continue;
        // OOB taps contribute exactly 0 (cd_roll=0 -> cd_prop=0;
        // d_roll=0 -> d_prop=0): skip them.
        const bool ok = (dr < 0 ? oku : dr > 0 ? okd : true) &&
                        (dc < 0 ? okl : dc > 0 ? okr : true);
        if (ok) {
          const int nb = base + dr * W_ + dc;
          const float d_r = d[nb], cd_r = cd[nb];
          float gp, cgp;
          if (dc != 0 && dr != 0) {  // corner: both axes active
            const float gxr = gx[nb], cgxr = cgx[nb];
            const float gyr = gy[nb], cgyr = cgy[nb];
            const float gxp =
                fmaf(cgxr, gxr, cgxgx) * __builtin_amdgcn_rcpf(cgxr + cgx_eps);
            const float gyp =
                fmaf(cgyr, gyr, cgygy) * __builtin_amdgcn_rcpf(cgyr + cgy_eps);
            gp = (dc > 0 ? -gxp : gxp) + (dr > 0 ? -gyp : gyp);
            // cg_prop = (cgx_prop+cgy_prop)/2 ; 2+EPS==2 in f32
            cgp = 0.25f * ((cgxr + cgx_c) + (cgyr + cgy_c));
          } else if (dc != 0) {  // horizontal tap: x axis only
            const float gxr = gx[nb], cgxr = cgx[nb];
            const float gxp =
                fmaf(cgxr, gxr, cgxgx) * __builtin_amdgcn_rcpf(cgxr + cgx_eps);
            gp = (dc > 0 ? -gxp : gxp);
            cgp = 0.5f * (cgxr + cgx_c);
          } else {  // vertical tap: y axis only
            const float gyr = gy[nb], cgyr = cgy[nb];
            const float gyp =
                fmaf(cgyr, gyr, cgygy) * __builtin_amdgcn_rcpf(cgyr + cgy_eps);
            gp = (dr > 0 ? -gyp : gyp);
            cgp = 0.5f * (cgyr + cgy_c);
          }
          const float dp = d_r * (1.f + gp);
          const float cdp = cd_r * fmaf(wg, cgp, 1.f) * inv1;
          const float s = sw_arr[r * 3 + cc];
          nom = fmaf(cdp * dp, s, nom);
          den = fmaf(cdp, s, den);
        }
      }
    }
    const float cs_c = den * inv_sum_sw;                               // cd_spatial
    const float csds_c = cs_c * (nom * __builtin_amdgcn_rcpf(den + EPS));  // cd_sp*d_sp

    // channel mix as outer-product accumulation: no/de stay in registers,
    // cwT[c][0..31] via 8 broadcast ds_read_b128
#pragma unroll
    for (int oq = 0; oq < 8; ++oq) {
      const float4 q = rec4[3 + oq];
      no[4 * oq + 0] = fmaf(csds_c, q.x, no[4 * oq + 0]);
      de[4 * oq + 0] = fmaf(cs_c, q.x, de[4 * oq + 0]);
      no[4 * oq + 1] = fmaf(csds_c, q.y, no[4 * oq + 1]);
      de[4 * oq + 1] = fmaf(cs_c, q.y, de[4 * oq + 1]);
      no[4 * oq + 2] = fmaf(csds_c, q.z, no[4 * oq + 2]);
      de[4 * oq + 2] = fmaf(cs_c, q.z, de[4 * oq + 2]);
      no[4 * oq + 3] = fmaf(csds_c, q.w, no[4 * oq + 3]);
      de[4 * oq + 3] = fmaf(cs_c, q.w, de[4 * oq + 3]);
    }
  }

#pragma unroll
  for (int o = 0; o < C_; ++o) {
    const int ob = base0 + o * HW_;
    out[ob] = no[o] * __builtin_amdgcn_rcpf(de[o] + EPS) + sP[1536 + o];
    out[B_ * C_ * HW_ + ob] = de[o] * inv_sum_cw;
  }
}

extern "C" void kernel_launch(void* const* d_in, const int* in_sizes, int n_in,
                              void* d_out, int out_size, void* d_ws, size_t ws_size,
                              hipStream_t stream) {
  const float* d_   = (const float*)d_in[0];
  const float* cd_  = (const float*)d_in[1];
  const float* gx_  = (const float*)d_in[2];
  const float* cgx_ = (const float*)d_in[3];
  const float* gy_  = (const float*)d_in[4];
  const float* cgy_ = (const float*)d_in[5];
  const float* wgr  = (const float*)d_in[6];
  const float* swt  = (const float*)d_in[7];
  const float* cwt  = (const float*)d_in[8];
  const float* bias = (const float*)d_in[9];
  float* out = (float*)d_out;
  float* P = (float*)d_ws;

  prep_kernel<<<1, 1024, 0, stream>>>(wgr, swt, cwt, bias, P);
  fused_kernel<<<512, 256, 0, stream>>>(d_, cd_, gx_, cgx_, gy_, cgy_, P, out);
}